// Round 11
// baseline (255.855 us; speedup 1.0000x reference)
//
#include <hip/hip_runtime.h>
#include <math.h>

#define IND   64
#define OUTD  101
#define RPB   64
#define NCT   7          // 7 col-tiles x 16 = 112 padded cols

typedef _Float16 half8 __attribute__((ext_vector_type(8)));
typedef float    f32x4 __attribute__((ext_vector_type(4)));

__global__ __launch_bounds__(64, 3) void density_kernel(
    const float* __restrict__ t,
    const float* __restrict__ x,
    const float* __restrict__ weight,
    const float* __restrict__ bias,
    const int*   __restrict__ num_grid,
    float* __restrict__ out1,
    float* __restrict__ out_interp,
    unsigned* __restrict__ tile_ctr,
    int n_rows, int n_tiles)
{
    __shared__ alignas(16) int liui[RPB];   // per-row packed (Li | Ui<<16)
    __shared__ float accL[RPB];             // per-row p[Li]
    __shared__ float accU[RPB];             // per-row p[Ui]

    const int lane = threadIdx.x;
    const int lc   = lane & 15;        // col-in-tile (R5 mapping)
    const int lg   = lane >> 4;        // k-group / row-group
    const float ngf = (float)num_grid[0];

    // ---- W fragments + bias: 63 VGPR, loaded ONCE per persistent block ----
    half8 wf[NCT][2];
    float biasv[NCT];
#pragma unroll
    for (int ct = 0; ct < NCT; ++ct) {
        const int col  = ct * 16 + lc;
        const int colc = (col < OUTD) ? col : (OUTD - 1);
        biasv[ct] = (col < OUTD) ? bias[col] : -1e30f;   // pads killed via bias
#pragma unroll
        for (int kg = 0; kg < 2; ++kg) {
            half8 h;
#pragma unroll
            for (int j = 0; j < 8; ++j)
                h[j] = (_Float16)weight[(kg * 32 + lg * 8 + j) * OUTD + colc];
            wf[ct][kg] = h;
        }
    }

    #define XPTR(TILE, RT) \
        ((const f32x4*)(x + (size_t)min((TILE) * RPB + (RT) * 16 + lc, n_rows - 1) * IND + lg * 8))

    // ---- work-stealing: grab first tile ----
    int tile;
    {
        unsigned t0 = 0;
        if (lane == 0) t0 = atomicAdd(tile_ctr, 1u);
        tile = __shfl((int)t0, 0, 64);
    }
    if (tile >= n_tiles) return;   // can't happen at 3072 blocks, but safe

    // ---- 2-buffer ping-pong x prefetch (static register names, rule #20) ----
    f32x4 pa0, pa1, pa2, pa3, pb0, pb1, pb2, pb3;
    {   // prime: tile rt=0 -> A buffer
        const f32x4* p = XPTR(tile, 0);
        pa0 = p[0]; pa1 = p[1]; pa2 = p[8]; pa3 = p[9];
    }

    // one row-tile: consume CUR regs, prefetch (PT,PR) into NXT regs
    #define PROCESS(RT, C0, C1, C2, C3, N0, N1, N2, N3, PT, PR)                  \
    {                                                                            \
        {   const f32x4* np = XPTR(PT, PR);                                      \
            N0 = np[0]; N1 = np[1]; N2 = np[8]; N3 = np[9]; }                    \
        half8 a0, a1;                                                            \
        _Pragma("unroll")                                                        \
        for (int i = 0; i < 4; ++i) {                                            \
            a0[i] = (_Float16)C0[i]; a0[4 + i] = (_Float16)C1[i];                \
            a1[i] = (_Float16)C2[i]; a1[4 + i] = (_Float16)C3[i];                \
        }                                                                        \
        f32x4 c[NCT];                                                            \
        _Pragma("unroll")                                                        \
        for (int ct = 0; ct < NCT; ++ct) {                                       \
            f32x4 ci = {biasv[ct], biasv[ct], biasv[ct], biasv[ct]};             \
            ci = __builtin_amdgcn_mfma_f32_16x16x32_f16(a0, wf[ct][0], ci,0,0,0);\
            ci = __builtin_amdgcn_mfma_f32_16x16x32_f16(a1, wf[ct][1], ci,0,0,0);\
            c[ct] = ci;                                                          \
        }                                                                        \
        float m[4], s[4];                                                        \
        _Pragma("unroll")                                                        \
        for (int j = 0; j < 4; ++j) {                                            \
            float mj = c[0][j];                                                  \
            _Pragma("unroll")                                                    \
            for (int ct = 1; ct < NCT; ++ct) mj = fmaxf(mj, c[ct][j]);           \
            _Pragma("unroll")                                                    \
            for (int d = 1; d < 16; d <<= 1) mj = fmaxf(mj, __shfl_xor(mj,d,64));\
            m[j] = mj; s[j] = 0.0f;                                              \
        }                                                                        \
        _Pragma("unroll")                                                        \
        for (int ct = 0; ct < NCT; ++ct)                                         \
            _Pragma("unroll")                                                    \
            for (int j = 0; j < 4; ++j) {                                        \
                const float e = __expf(c[ct][j] - m[j]);                         \
                c[ct][j] = e; s[j] += e;                                         \
            }                                                                    \
        _Pragma("unroll")                                                        \
        for (int j = 0; j < 4; ++j) {                                            \
            _Pragma("unroll")                                                    \
            for (int d = 1; d < 16; d <<= 1) s[j] += __shfl_xor(s[j], d, 64);    \
            float inv = __builtin_amdgcn_rcpf(s[j]);                             \
            inv = inv * (2.0f - s[j] * inv);                                     \
            s[j] = inv;                                                          \
        }                                                                        \
        _Pragma("unroll")                                                        \
        for (int ct = 0; ct < NCT; ++ct)                                         \
            _Pragma("unroll")                                                    \
            for (int j = 0; j < 4; ++j) c[ct][j] *= s[j];                        \
        const int rbase = row0 + RT * 16 + lg * 4;                               \
        _Pragma("unroll")                                                        \
        for (int j = 0; j < 4; ++j) {                                            \
            const int r = rbase + j;                                             \
            if (r < n_rows) {                                                    \
                float* orow = out1 + (size_t)r * OUTD;                           \
                _Pragma("unroll")                                                \
                for (int ct = 0; ct < NCT; ++ct) {                               \
                    const int col = ct * 16 + lc;                                \
                    if (col < OUTD) orow[col] = c[ct][j];                        \
                }                                                                \
            }                                                                    \
        }                                                                        \
        const int rl = RT * 16 + lg * 4;                                         \
        int lup[4];                                                              \
        *(int4*)lup = *(const int4*)&liui[rl];                                   \
        _Pragma("unroll")                                                        \
        for (int j = 0; j < 4; ++j) {                                            \
            const int LiR = lup[j] & 0xffff;                                     \
            const int UiR = lup[j] >> 16;                                        \
            const int ctL = LiR >> 4, lcL = LiR & 15;                            \
            const int ctU = UiR >> 4, lcU = UiR & 15;                            \
            float pL = 0.0f, pU = 0.0f;                                          \
            _Pragma("unroll")                                                    \
            for (int ct = 0; ct < NCT; ++ct) {                                   \
                pL = (ct == ctL) ? c[ct][j] : pL;                                \
                pU = (ct == ctU) ? c[ct][j] : pU;                                \
            }                                                                    \
            if (lc == lcL) accL[rl + j] = pL;                                    \
            if (lc == lcU) accU[rl + j] = pU;                                    \
        }                                                                        \
    }

    while (true) {
        const int row0 = tile * RPB;

        // grab NEXT tile now so PROCESS(3) can prefetch its rt=0
        int next;
        {
            unsigned nx = 0;
            if (lane == 0) nx = atomicAdd(tile_ctr, 1u);
            next = __shfl((int)nx, 0, 64);
        }
        const int pt = (next < n_tiles) ? next : tile;   // clamp: dummy reload

        // own-row interp indices -> LDS broadcast (1-wave block: cheap sync)
        const int gr  = row0 + lane;
        const int grc = (gr < n_rows) ? gr : (n_rows - 1);
        const float tB = t[grc] * ngf;
        const float Uf = ceilf(tB);
        const float inter = 1.0f - (Uf - tB);
        float Lf = Uf - 1.0f;
        if (Lf < 0.0f) Lf += 1.0f;
        liui[lane] = ((int)Lf) | (((int)Uf) << 16);
        __syncthreads();

        PROCESS(0, pa0, pa1, pa2, pa3, pb0, pb1, pb2, pb3, tile, 1)
        PROCESS(1, pb0, pb1, pb2, pb3, pa0, pa1, pa2, pa3, tile, 2)
        PROCESS(2, pa0, pa1, pa2, pa3, pb0, pb1, pb2, pb3, tile, 3)
        PROCESS(3, pb0, pb1, pb2, pb3, pa0, pa1, pa2, pa3, pt,   0)

        __syncthreads();

        // interp: lane = row, fp32 lerp
        if (gr < n_rows) {
            const float Lv = accL[lane];
            const float Uv = accU[lane];
            out_interp[gr] = Lv + (Uv - Lv) * inter;
        }

        if (next >= n_tiles) break;
        tile = next;
    }
    #undef PROCESS
    #undef XPTR
}

extern "C" void kernel_launch(void* const* d_in, const int* in_sizes, int n_in,
                              void* d_out, int out_size, void* d_ws, size_t ws_size,
                              hipStream_t stream) {
    const float* t  = (const float*)d_in[0];
    const float* x  = (const float*)d_in[1];
    const float* w  = (const float*)d_in[2];
    const float* b  = (const float*)d_in[3];
    const int*   ng = (const int*)d_in[4];
    const int n_rows = in_sizes[0];

    float* out1       = (float*)d_out;
    float* out_interp = out1 + (size_t)n_rows * OUTD;
    unsigned* tile_ctr = (unsigned*)d_ws;

    // reset work-stealing counter each launch (async memset is capture-legal)
    hipMemsetAsync(tile_ctr, 0, sizeof(unsigned), stream);

    const int n_tiles  = (n_rows + RPB - 1) / RPB;   // 15625
    const int n_blocks = 3072;                       // 3 waves/SIMD x 1024 SIMDs
    density_kernel<<<dim3(n_blocks), dim3(64), 0, stream>>>(
        t, x, w, b, ng, out1, out_interp, tile_ctr, n_rows, n_tiles);
}

// Round 12
// 242.057 us; speedup vs baseline: 1.0570x; 1.0570x over previous
//
#include <hip/hip_runtime.h>
#include <math.h>

#define IND   64
#define OUTD  101
#define RPB   64
#define NCT   7          // 7 col-tiles x 16 = 112 padded cols

typedef _Float16 half8 __attribute__((ext_vector_type(8)));
typedef float    f32x4 __attribute__((ext_vector_type(4)));

__global__ __launch_bounds__(64, 4) void density_kernel(
    const float* __restrict__ t,
    const float* __restrict__ x,
    const float* __restrict__ weight,
    const float* __restrict__ bias,
    const int*   __restrict__ num_grid,
    float* __restrict__ out1,
    float* __restrict__ out_interp,
    int n_rows, int n_tiles, int n_blocks)
{
    __shared__ alignas(16) int liui[RPB];   // per-row packed (Li | Ui<<16)
    __shared__ float accL[RPB];             // per-row p[Li]
    __shared__ float accU[RPB];             // per-row p[Ui]

    const int lane = threadIdx.x;
    const int lc   = lane & 15;        // col-in-tile (R5 mapping)
    const int lg   = lane >> 4;        // k-group / row-group
    const float ngf = (float)num_grid[0];

    // ---- W fragments + bias (compiler chooses residency; demand ~84 VGPR) ----
    half8 wf[NCT][2];
    float biasv[NCT];
#pragma unroll
    for (int ct = 0; ct < NCT; ++ct) {
        const int col  = ct * 16 + lc;
        const int colc = (col < OUTD) ? col : (OUTD - 1);
        biasv[ct] = (col < OUTD) ? bias[col] : -1e30f;   // pads killed via bias
#pragma unroll
        for (int kg = 0; kg < 2; ++kg) {
            half8 h;
#pragma unroll
            for (int j = 0; j < 8; ++j)
                h[j] = (_Float16)weight[(kg * 32 + lg * 8 + j) * OUTD + colc];
            wf[ct][kg] = h;
        }
    }

    #define XPTR(TILE, RT) \
        ((const f32x4*)(x + (size_t)min((TILE) * RPB + (RT) * 16 + lc, n_rows - 1) * IND + lg * 8))

    // ---- 2-buffer ping-pong x prefetch (static register names, rule #20) ----
    f32x4 pa0, pa1, pa2, pa3, pb0, pb1, pb2, pb3;

    int tile = blockIdx.x;
    {   // prime: tile rt=0 -> A buffer
        const f32x4* p = XPTR(tile, 0);
        pa0 = p[0]; pa1 = p[1]; pa2 = p[8]; pa3 = p[9];
    }

    // one row-tile: consume CUR regs, prefetch (PT,PR) into NXT regs
    #define PROCESS(RT, C0, C1, C2, C3, N0, N1, N2, N3, PT, PR)                  \
    {                                                                            \
        {   const f32x4* np = XPTR(PT, PR);                                      \
            N0 = np[0]; N1 = np[1]; N2 = np[8]; N3 = np[9]; }                    \
        half8 a0, a1;                                                            \
        _Pragma("unroll")                                                        \
        for (int i = 0; i < 4; ++i) {                                            \
            a0[i] = (_Float16)C0[i]; a0[4 + i] = (_Float16)C1[i];                \
            a1[i] = (_Float16)C2[i]; a1[4 + i] = (_Float16)C3[i];                \
        }                                                                        \
        f32x4 c[NCT];                                                            \
        _Pragma("unroll")                                                        \
        for (int ct = 0; ct < NCT; ++ct) {                                       \
            f32x4 ci = {biasv[ct], biasv[ct], biasv[ct], biasv[ct]};             \
            ci = __builtin_amdgcn_mfma_f32_16x16x32_f16(a0, wf[ct][0], ci,0,0,0);\
            ci = __builtin_amdgcn_mfma_f32_16x16x32_f16(a1, wf[ct][1], ci,0,0,0);\
            c[ct] = ci;                                                          \
        }                                                                        \
        float m[4], s[4];                                                        \
        _Pragma("unroll")                                                        \
        for (int j = 0; j < 4; ++j) {                                            \
            float mj = c[0][j];                                                  \
            _Pragma("unroll")                                                    \
            for (int ct = 1; ct < NCT; ++ct) mj = fmaxf(mj, c[ct][j]);           \
            _Pragma("unroll")                                                    \
            for (int d = 1; d < 16; d <<= 1) mj = fmaxf(mj, __shfl_xor(mj,d,64));\
            m[j] = mj; s[j] = 0.0f;                                              \
        }                                                                        \
        _Pragma("unroll")                                                        \
        for (int ct = 0; ct < NCT; ++ct)                                         \
            _Pragma("unroll")                                                    \
            for (int j = 0; j < 4; ++j) {                                        \
                const float e = __expf(c[ct][j] - m[j]);                         \
                c[ct][j] = e; s[j] += e;                                         \
            }                                                                    \
        _Pragma("unroll")                                                        \
        for (int j = 0; j < 4; ++j) {                                            \
            _Pragma("unroll")                                                    \
            for (int d = 1; d < 16; d <<= 1) s[j] += __shfl_xor(s[j], d, 64);    \
            float inv = __builtin_amdgcn_rcpf(s[j]);                             \
            inv = inv * (2.0f - s[j] * inv);                                     \
            s[j] = inv;                                                          \
        }                                                                        \
        _Pragma("unroll")                                                        \
        for (int ct = 0; ct < NCT; ++ct)                                         \
            _Pragma("unroll")                                                    \
            for (int j = 0; j < 4; ++j) c[ct][j] *= s[j];                        \
        const int rbase = row0 + RT * 16 + lg * 4;                               \
        _Pragma("unroll")                                                        \
        for (int j = 0; j < 4; ++j) {                                            \
            const int r = rbase + j;                                             \
            if (r < n_rows) {                                                    \
                float* orow = out1 + (size_t)r * OUTD;                           \
                _Pragma("unroll")                                                \
                for (int ct = 0; ct < NCT; ++ct) {                               \
                    const int col = ct * 16 + lc;                                \
                    if (col < OUTD) orow[col] = c[ct][j];                        \
                }                                                                \
            }                                                                    \
        }                                                                        \
        const int rl = RT * 16 + lg * 4;                                         \
        int lup[4];                                                              \
        *(int4*)lup = *(const int4*)&liui[rl];                                   \
        _Pragma("unroll")                                                        \
        for (int j = 0; j < 4; ++j) {                                            \
            const int LiR = lup[j] & 0xffff;                                     \
            const int UiR = lup[j] >> 16;                                        \
            const int ctL = LiR >> 4, lcL = LiR & 15;                            \
            const int ctU = UiR >> 4, lcU = UiR & 15;                            \
            float pL = 0.0f, pU = 0.0f;                                          \
            _Pragma("unroll")                                                    \
            for (int ct = 0; ct < NCT; ++ct) {                                   \
                pL = (ct == ctL) ? c[ct][j] : pL;                                \
                pU = (ct == ctU) ? c[ct][j] : pU;                                \
            }                                                                    \
            if (lc == lcL) accL[rl + j] = pL;                                    \
            if (lc == lcU) accU[rl + j] = pU;                                    \
        }                                                                        \
    }

    for (; tile < n_tiles; tile += n_blocks) {
        const int row0 = tile * RPB;

        // own-row interp indices -> LDS broadcast (1-wave block: cheap sync)
        const int gr  = row0 + lane;
        const int grc = (gr < n_rows) ? gr : (n_rows - 1);
        const float tB = t[grc] * ngf;
        const float Uf = ceilf(tB);
        const float inter = 1.0f - (Uf - tB);
        float Lf = Uf - 1.0f;
        if (Lf < 0.0f) Lf += 1.0f;
        liui[lane] = ((int)Lf) | (((int)Uf) << 16);
        __syncthreads();

        const int  ntile = tile + n_blocks;
        const int  pt    = (ntile < n_tiles) ? ntile : tile;   // clamp: dummy reload

        PROCESS(0, pa0, pa1, pa2, pa3, pb0, pb1, pb2, pb3, tile, 1)
        PROCESS(1, pb0, pb1, pb2, pb3, pa0, pa1, pa2, pa3, tile, 2)
        PROCESS(2, pa0, pa1, pa2, pa3, pb0, pb1, pb2, pb3, tile, 3)
        PROCESS(3, pb0, pb1, pb2, pb3, pa0, pa1, pa2, pa3, pt,   0)

        __syncthreads();

        // interp: lane = row, fp32 lerp
        if (gr < n_rows) {
            const float Lv = accL[lane];
            const float Uv = accU[lane];
            out_interp[gr] = Lv + (Uv - Lv) * inter;
        }
    }
    #undef PROCESS
    #undef XPTR
}

extern "C" void kernel_launch(void* const* d_in, const int* in_sizes, int n_in,
                              void* d_out, int out_size, void* d_ws, size_t ws_size,
                              hipStream_t stream) {
    const float* t  = (const float*)d_in[0];
    const float* x  = (const float*)d_in[1];
    const float* w  = (const float*)d_in[2];
    const float* b  = (const float*)d_in[3];
    const int*   ng = (const int*)d_in[4];
    const int n_rows = in_sizes[0];

    float* out1       = (float*)d_out;
    float* out_interp = out1 + (size_t)n_rows * OUTD;

    const int n_tiles  = (n_rows + RPB - 1) / RPB;   // 15625
    const int n_blocks = 4096;                       // 4 waves/SIMD x 1024 SIMDs
    density_kernel<<<dim3(n_blocks), dim3(64), 0, stream>>>(
        t, x, w, b, ng, out1, out_interp, n_rows, n_tiles, n_blocks);
}

// Round 13
// 170.622 us; speedup vs baseline: 1.4995x; 1.4187x over previous
//
#include <hip/hip_runtime.h>
#include <math.h>

#define IND   64
#define OUTD  101
#define RPB   64
#define NCT   7          // 7 col-tiles x 16 = 112 padded cols

typedef _Float16 half8 __attribute__((ext_vector_type(8)));
typedef float    f32x4 __attribute__((ext_vector_type(4)));

// (64,3): keeps the allocator at ~84 VGPR (measured R11). Do NOT use (64,4):
// it squeezes to 64 VGPR and spills (R6, R12: FETCH +233 MB of scratch).
// Runtime occupancy comes from resources (84<=128 -> 4 waves/SIMD fits),
// so we raise occupancy via GRID SIZE, not via the bound.
__global__ __launch_bounds__(64, 3) void density_kernel(
    const float* __restrict__ t,
    const float* __restrict__ x,
    const float* __restrict__ weight,
    const float* __restrict__ bias,
    const int*   __restrict__ num_grid,
    float* __restrict__ out1,
    float* __restrict__ out_interp,
    int n_rows, int n_tiles, int n_blocks)
{
    __shared__ alignas(16) int liui[RPB];   // per-row packed (Li | Ui<<16)
    __shared__ float accL[RPB];             // per-row p[Li]
    __shared__ float accU[RPB];             // per-row p[Ui]

    const int lane = threadIdx.x;
    const int lc   = lane & 15;        // col-in-tile (R5 mapping)
    const int lg   = lane >> 4;        // k-group / row-group
    const float ngf = (float)num_grid[0];

    // ---- W fragments + bias (compiler chooses residency; demand ~84 VGPR) ----
    half8 wf[NCT][2];
    float biasv[NCT];
#pragma unroll
    for (int ct = 0; ct < NCT; ++ct) {
        const int col  = ct * 16 + lc;
        const int colc = (col < OUTD) ? col : (OUTD - 1);
        biasv[ct] = (col < OUTD) ? bias[col] : -1e30f;   // pads killed via bias
#pragma unroll
        for (int kg = 0; kg < 2; ++kg) {
            half8 h;
#pragma unroll
            for (int j = 0; j < 8; ++j)
                h[j] = (_Float16)weight[(kg * 32 + lg * 8 + j) * OUTD + colc];
            wf[ct][kg] = h;
        }
    }

    #define XPTR(TILE, RT) \
        ((const f32x4*)(x + (size_t)min((TILE) * RPB + (RT) * 16 + lc, n_rows - 1) * IND + lg * 8))

    // ---- 2-buffer ping-pong x prefetch (static register names, rule #20) ----
    f32x4 pa0, pa1, pa2, pa3, pb0, pb1, pb2, pb3;

    int tile = blockIdx.x;
    {   // prime: tile rt=0 -> A buffer
        const f32x4* p = XPTR(tile, 0);
        pa0 = p[0]; pa1 = p[1]; pa2 = p[8]; pa3 = p[9];
    }

    // one row-tile: consume CUR regs, prefetch (PT,PR) into NXT regs
    #define PROCESS(RT, C0, C1, C2, C3, N0, N1, N2, N3, PT, PR)                  \
    {                                                                            \
        {   const f32x4* np = XPTR(PT, PR);                                      \
            N0 = np[0]; N1 = np[1]; N2 = np[8]; N3 = np[9]; }                    \
        half8 a0, a1;                                                            \
        _Pragma("unroll")                                                        \
        for (int i = 0; i < 4; ++i) {                                            \
            a0[i] = (_Float16)C0[i]; a0[4 + i] = (_Float16)C1[i];                \
            a1[i] = (_Float16)C2[i]; a1[4 + i] = (_Float16)C3[i];                \
        }                                                                        \
        f32x4 c[NCT];                                                            \
        _Pragma("unroll")                                                        \
        for (int ct = 0; ct < NCT; ++ct) {                                       \
            f32x4 ci = {biasv[ct], biasv[ct], biasv[ct], biasv[ct]};             \
            ci = __builtin_amdgcn_mfma_f32_16x16x32_f16(a0, wf[ct][0], ci,0,0,0);\
            ci = __builtin_amdgcn_mfma_f32_16x16x32_f16(a1, wf[ct][1], ci,0,0,0);\
            c[ct] = ci;                                                          \
        }                                                                        \
        float m[4], s[4];                                                        \
        _Pragma("unroll")                                                        \
        for (int j = 0; j < 4; ++j) {                                            \
            float mj = c[0][j];                                                  \
            _Pragma("unroll")                                                    \
            for (int ct = 1; ct < NCT; ++ct) mj = fmaxf(mj, c[ct][j]);           \
            _Pragma("unroll")                                                    \
            for (int d = 1; d < 16; d <<= 1) mj = fmaxf(mj, __shfl_xor(mj,d,64));\
            m[j] = mj; s[j] = 0.0f;                                              \
        }                                                                        \
        _Pragma("unroll")                                                        \
        for (int ct = 0; ct < NCT; ++ct)                                         \
            _Pragma("unroll")                                                    \
            for (int j = 0; j < 4; ++j) {                                        \
                const float e = __expf(c[ct][j] - m[j]);                         \
                c[ct][j] = e; s[j] += e;                                         \
            }                                                                    \
        _Pragma("unroll")                                                        \
        for (int j = 0; j < 4; ++j) {                                            \
            _Pragma("unroll")                                                    \
            for (int d = 1; d < 16; d <<= 1) s[j] += __shfl_xor(s[j], d, 64);    \
            float inv = __builtin_amdgcn_rcpf(s[j]);                             \
            inv = inv * (2.0f - s[j] * inv);                                     \
            s[j] = inv;                                                          \
        }                                                                        \
        _Pragma("unroll")                                                        \
        for (int ct = 0; ct < NCT; ++ct)                                         \
            _Pragma("unroll")                                                    \
            for (int j = 0; j < 4; ++j) c[ct][j] *= s[j];                        \
        const int rbase = row0 + RT * 16 + lg * 4;                               \
        _Pragma("unroll")                                                        \
        for (int j = 0; j < 4; ++j) {                                            \
            const int r = rbase + j;                                             \
            if (r < n_rows) {                                                    \
                float* orow = out1 + (size_t)r * OUTD;                           \
                _Pragma("unroll")                                                \
                for (int ct = 0; ct < NCT; ++ct) {                               \
                    const int col = ct * 16 + lc;                                \
                    if (col < OUTD) orow[col] = c[ct][j];                        \
                }                                                                \
            }                                                                    \
        }                                                                        \
        const int rl = RT * 16 + lg * 4;                                         \
        int lup[4];                                                              \
        *(int4*)lup = *(const int4*)&liui[rl];                                   \
        _Pragma("unroll")                                                        \
        for (int j = 0; j < 4; ++j) {                                            \
            const int LiR = lup[j] & 0xffff;                                     \
            const int UiR = lup[j] >> 16;                                        \
            const int ctL = LiR >> 4, lcL = LiR & 15;                            \
            const int ctU = UiR >> 4, lcU = UiR & 15;                            \
            float pL = 0.0f, pU = 0.0f;                                          \
            _Pragma("unroll")                                                    \
            for (int ct = 0; ct < NCT; ++ct) {                                   \
                pL = (ct == ctL) ? c[ct][j] : pL;                                \
                pU = (ct == ctU) ? c[ct][j] : pU;                                \
            }                                                                    \
            if (lc == lcL) accL[rl + j] = pL;                                    \
            if (lc == lcU) accU[rl + j] = pU;                                    \
        }                                                                        \
    }

    for (; tile < n_tiles; tile += n_blocks) {
        const int row0 = tile * RPB;

        // own-row interp indices -> LDS broadcast (1-wave block: cheap sync)
        const int gr  = row0 + lane;
        const int grc = (gr < n_rows) ? gr : (n_rows - 1);
        const float tB = t[grc] * ngf;
        const float Uf = ceilf(tB);
        const float inter = 1.0f - (Uf - tB);
        float Lf = Uf - 1.0f;
        if (Lf < 0.0f) Lf += 1.0f;
        liui[lane] = ((int)Lf) | (((int)Uf) << 16);
        __syncthreads();

        const int  ntile = tile + n_blocks;
        const int  pt    = (ntile < n_tiles) ? ntile : tile;   // clamp: dummy reload

        PROCESS(0, pa0, pa1, pa2, pa3, pb0, pb1, pb2, pb3, tile, 1)
        PROCESS(1, pb0, pb1, pb2, pb3, pa0, pa1, pa2, pa3, tile, 2)
        PROCESS(2, pa0, pa1, pa2, pa3, pb0, pb1, pb2, pb3, tile, 3)
        PROCESS(3, pb0, pb1, pb2, pb3, pa0, pa1, pa2, pa3, pt,   0)

        __syncthreads();

        // interp: lane = row, fp32 lerp
        if (gr < n_rows) {
            const float Lv = accL[lane];
            const float Uv = accU[lane];
            out_interp[gr] = Lv + (Uv - Lv) * inter;
        }
    }
    #undef PROCESS
    #undef XPTR
}

extern "C" void kernel_launch(void* const* d_in, const int* in_sizes, int n_in,
                              void* d_out, int out_size, void* d_ws, size_t ws_size,
                              hipStream_t stream) {
    const float* t  = (const float*)d_in[0];
    const float* x  = (const float*)d_in[1];
    const float* w  = (const float*)d_in[2];
    const float* b  = (const float*)d_in[3];
    const int*   ng = (const int*)d_in[4];
    const int n_rows = in_sizes[0];

    float* out1       = (float*)d_out;
    float* out_interp = out1 + (size_t)n_rows * OUTD;

    const int n_tiles  = (n_rows + RPB - 1) / RPB;   // 15625
    // 4096 blocks: 16 one-wave blocks/CU (VGPR 84 <= 128 -> 4 waves/SIMD fit).
    // Occupancy raised by grid, NOT by launch_bounds (which would spill).
    const int n_blocks = 4096;
    density_kernel<<<dim3(n_blocks), dim3(64), 0, stream>>>(
        t, x, w, b, ng, out1, out_interp, n_rows, n_tiles, n_blocks);
}

// Round 14
// 170.362 us; speedup vs baseline: 1.5018x; 1.0015x over previous
//
#include <hip/hip_runtime.h>
#include <math.h>

#define IND   64
#define OUTD  101
#define RPB   64
#define NCT   7          // 7 col-tiles x 16 = 112 padded cols

typedef _Float16 half8 __attribute__((ext_vector_type(8)));
typedef float    f32x4 __attribute__((ext_vector_type(4)));

// (64,3): keeps the allocator at ~84 VGPR (measured R11/R13). (64,4) squeezes
// to 64 VGPR and spills (R6, R12). Occupancy is raised via grid size.
//
// NO __syncthreads in this kernel: blocks are ONE wave (64 threads). LDS
// accesses within a wave are program-ordered (lgkmcnt), so barriers are
// semantically unneeded -- and each barrier forced a full
// `s_waitcnt vmcnt(0)` drain of ~112 outstanding out1 stores per tile,
// which R13 showed to be the occupancy-insensitive serial stall.
__global__ __launch_bounds__(64, 3) void density_kernel(
    const float* __restrict__ t,
    const float* __restrict__ x,
    const float* __restrict__ weight,
    const float* __restrict__ bias,
    const int*   __restrict__ num_grid,
    float* __restrict__ out1,
    float* __restrict__ out_interp,
    int n_rows, int n_tiles, int n_blocks)
{
    __shared__ alignas(16) int liui[RPB];   // per-row packed (Li | Ui<<16)
    __shared__ float accL[RPB];             // per-row p[Li]
    __shared__ float accU[RPB];             // per-row p[Ui]

    const int lane = threadIdx.x;
    const int lc   = lane & 15;        // col-in-tile (R5 mapping)
    const int lg   = lane >> 4;        // k-group / row-group
    const float ngf = (float)num_grid[0];

    // ---- W fragments + bias (compiler chooses residency; demand ~84 VGPR) ----
    half8 wf[NCT][2];
    float biasv[NCT];
#pragma unroll
    for (int ct = 0; ct < NCT; ++ct) {
        const int col  = ct * 16 + lc;
        const int colc = (col < OUTD) ? col : (OUTD - 1);
        biasv[ct] = (col < OUTD) ? bias[col] : -1e30f;   // pads killed via bias
#pragma unroll
        for (int kg = 0; kg < 2; ++kg) {
            half8 h;
#pragma unroll
            for (int j = 0; j < 8; ++j)
                h[j] = (_Float16)weight[(kg * 32 + lg * 8 + j) * OUTD + colc];
            wf[ct][kg] = h;
        }
    }

    #define XPTR(TILE, RT) \
        ((const f32x4*)(x + (size_t)min((TILE) * RPB + (RT) * 16 + lc, n_rows - 1) * IND + lg * 8))

    // ---- 2-buffer ping-pong x prefetch (static register names, rule #20) ----
    f32x4 pa0, pa1, pa2, pa3, pb0, pb1, pb2, pb3;

    int tile = blockIdx.x;
    {   // prime: tile rt=0 -> A buffer
        const f32x4* p = XPTR(tile, 0);
        pa0 = p[0]; pa1 = p[1]; pa2 = p[8]; pa3 = p[9];
    }

    // one row-tile: consume CUR regs, prefetch (PT,PR) into NXT regs
    #define PROCESS(RT, C0, C1, C2, C3, N0, N1, N2, N3, PT, PR)                  \
    {                                                                            \
        {   const f32x4* np = XPTR(PT, PR);                                      \
            N0 = np[0]; N1 = np[1]; N2 = np[8]; N3 = np[9]; }                    \
        half8 a0, a1;                                                            \
        _Pragma("unroll")                                                        \
        for (int i = 0; i < 4; ++i) {                                            \
            a0[i] = (_Float16)C0[i]; a0[4 + i] = (_Float16)C1[i];                \
            a1[i] = (_Float16)C2[i]; a1[4 + i] = (_Float16)C3[i];                \
        }                                                                        \
        f32x4 c[NCT];                                                            \
        _Pragma("unroll")                                                        \
        for (int ct = 0; ct < NCT; ++ct) {                                       \
            f32x4 ci = {biasv[ct], biasv[ct], biasv[ct], biasv[ct]};             \
            ci = __builtin_amdgcn_mfma_f32_16x16x32_f16(a0, wf[ct][0], ci,0,0,0);\
            ci = __builtin_amdgcn_mfma_f32_16x16x32_f16(a1, wf[ct][1], ci,0,0,0);\
            c[ct] = ci;                                                          \
        }                                                                        \
        float m[4], s[4];                                                        \
        _Pragma("unroll")                                                        \
        for (int j = 0; j < 4; ++j) {                                            \
            float mj = c[0][j];                                                  \
            _Pragma("unroll")                                                    \
            for (int ct = 1; ct < NCT; ++ct) mj = fmaxf(mj, c[ct][j]);           \
            _Pragma("unroll")                                                    \
            for (int d = 1; d < 16; d <<= 1) mj = fmaxf(mj, __shfl_xor(mj,d,64));\
            m[j] = mj; s[j] = 0.0f;                                              \
        }                                                                        \
        _Pragma("unroll")                                                        \
        for (int ct = 0; ct < NCT; ++ct)                                         \
            _Pragma("unroll")                                                    \
            for (int j = 0; j < 4; ++j) {                                        \
                const float e = __expf(c[ct][j] - m[j]);                         \
                c[ct][j] = e; s[j] += e;                                         \
            }                                                                    \
        _Pragma("unroll")                                                        \
        for (int j = 0; j < 4; ++j) {                                            \
            _Pragma("unroll")                                                    \
            for (int d = 1; d < 16; d <<= 1) s[j] += __shfl_xor(s[j], d, 64);    \
            float inv = __builtin_amdgcn_rcpf(s[j]);                             \
            inv = inv * (2.0f - s[j] * inv);                                     \
            s[j] = inv;                                                          \
        }                                                                        \
        _Pragma("unroll")                                                        \
        for (int ct = 0; ct < NCT; ++ct)                                         \
            _Pragma("unroll")                                                    \
            for (int j = 0; j < 4; ++j) c[ct][j] *= s[j];                        \
        const int rbase = row0 + RT * 16 + lg * 4;                               \
        _Pragma("unroll")                                                        \
        for (int j = 0; j < 4; ++j) {                                            \
            const int r = rbase + j;                                             \
            if (r < n_rows) {                                                    \
                float* orow = out1 + (size_t)r * OUTD;                           \
                _Pragma("unroll")                                                \
                for (int ct = 0; ct < NCT; ++ct) {                               \
                    const int col = ct * 16 + lc;                                \
                    if (col < OUTD) orow[col] = c[ct][j];                        \
                }                                                                \
            }                                                                    \
        }                                                                        \
        const int rl = RT * 16 + lg * 4;                                         \
        int lup[4];                                                              \
        *(int4*)lup = *(const int4*)&liui[rl];                                   \
        _Pragma("unroll")                                                        \
        for (int j = 0; j < 4; ++j) {                                            \
            const int LiR = lup[j] & 0xffff;                                     \
            const int UiR = lup[j] >> 16;                                        \
            const int ctL = LiR >> 4, lcL = LiR & 15;                            \
            const int ctU = UiR >> 4, lcU = UiR & 15;                            \
            float pL = 0.0f, pU = 0.0f;                                          \
            _Pragma("unroll")                                                    \
            for (int ct = 0; ct < NCT; ++ct) {                                   \
                pL = (ct == ctL) ? c[ct][j] : pL;                                \
                pU = (ct == ctU) ? c[ct][j] : pU;                                \
            }                                                                    \
            if (lc == lcL) accL[rl + j] = pL;                                    \
            if (lc == lcU) accU[rl + j] = pU;                                    \
        }                                                                        \
    }

    for (; tile < n_tiles; tile += n_blocks) {
        const int row0 = tile * RPB;

        // own-row interp indices -> LDS broadcast (same-wave ordering via
        // lgkmcnt; no barrier needed in a 1-wave block)
        const int gr  = row0 + lane;
        const int grc = (gr < n_rows) ? gr : (n_rows - 1);
        const float tB = t[grc] * ngf;
        const float Uf = ceilf(tB);
        const float inter = 1.0f - (Uf - tB);
        float Lf = Uf - 1.0f;
        if (Lf < 0.0f) Lf += 1.0f;
        liui[lane] = ((int)Lf) | (((int)Uf) << 16);

        const int  ntile = tile + n_blocks;
        const int  pt    = (ntile < n_tiles) ? ntile : tile;   // clamp: dummy reload

        PROCESS(0, pa0, pa1, pa2, pa3, pb0, pb1, pb2, pb3, tile, 1)
        PROCESS(1, pb0, pb1, pb2, pb3, pa0, pa1, pa2, pa3, tile, 2)
        PROCESS(2, pa0, pa1, pa2, pa3, pb0, pb1, pb2, pb3, tile, 3)
        PROCESS(3, pb0, pb1, pb2, pb3, pa0, pa1, pa2, pa3, pt,   0)

        // interp: lane = row, fp32 lerp (accL/accU written by this wave above)
        if (gr < n_rows) {
            const float Lv = accL[lane];
            const float Uv = accU[lane];
            out_interp[gr] = Lv + (Uv - Lv) * inter;
        }
    }
    #undef PROCESS
    #undef XPTR
}

extern "C" void kernel_launch(void* const* d_in, const int* in_sizes, int n_in,
                              void* d_out, int out_size, void* d_ws, size_t ws_size,
                              hipStream_t stream) {
    const float* t  = (const float*)d_in[0];
    const float* x  = (const float*)d_in[1];
    const float* w  = (const float*)d_in[2];
    const float* b  = (const float*)d_in[3];
    const int*   ng = (const int*)d_in[4];
    const int n_rows = in_sizes[0];

    float* out1       = (float*)d_out;
    float* out_interp = out1 + (size_t)n_rows * OUTD;

    const int n_tiles  = (n_rows + RPB - 1) / RPB;   // 15625
    const int n_blocks = 4096;                       // 16 one-wave blocks/CU
    density_kernel<<<dim3(n_blocks), dim3(64), 0, stream>>>(
        t, x, w, b, ng, out1, out_interp, n_rows, n_tiles, n_blocks);
}

// Round 15
// 149.401 us; speedup vs baseline: 1.7125x; 1.1403x over previous
//
#include <hip/hip_runtime.h>
#include <math.h>

#define IND   64
#define OUTD  101
#define RPB   64
#define NCT   7              // 7 col-tiles x 16 = 112 padded cols
#define LROW  101            // LDS row stride (words); 3-way max write conflict
#define HALF_WORDS (32 * OUTD)   // 3232 words = 12928 B per half-tile

typedef _Float16 half8 __attribute__((ext_vector_type(8)));
typedef float    f32x4 __attribute__((ext_vector_type(4)));

// (64,3): allocator lands at ~84-125 VGPR, no spill (R6/R12 lesson: never cap
// below demand). One wave per block, NO barriers (R14: in-wave LDS is
// program-ordered). NEW in R15: out1 is staged in LDS per 32-row half-tile
// and drained as 13 contiguous 1KB dwordx4 stores (fill-pattern) instead of
// 112 scalar dword stores per tile -- the store stream, not TLP or barriers,
// is the hypothesized 170us limiter (R13/R14 double-null).
__global__ __launch_bounds__(64, 3) void density_kernel(
    const float* __restrict__ t,
    const float* __restrict__ x,
    const float* __restrict__ weight,
    const float* __restrict__ bias,
    const int*   __restrict__ num_grid,
    float* __restrict__ out1,
    float* __restrict__ out_interp,
    int n_rows, int n_tiles, int n_blocks)
{
    __shared__ float ptile[HALF_WORDS];   // 12928 B, reused for both halves

    const int lane = threadIdx.x;
    const int lc   = lane & 15;        // col-in-tile (R5 mapping)
    const int lg   = lane >> 4;        // k-group / row-group
    const float ngf = (float)num_grid[0];

    // ---- W fragments + bias ----
    half8 wf[NCT][2];
    float biasv[NCT];
#pragma unroll
    for (int ct = 0; ct < NCT; ++ct) {
        const int col  = ct * 16 + lc;
        const int colc = (col < OUTD) ? col : (OUTD - 1);
        biasv[ct] = (col < OUTD) ? bias[col] : -1e30f;   // pads killed via bias
#pragma unroll
        for (int kg = 0; kg < 2; ++kg) {
            half8 h;
#pragma unroll
            for (int j = 0; j < 8; ++j)
                h[j] = (_Float16)weight[(kg * 32 + lg * 8 + j) * OUTD + colc];
            wf[ct][kg] = h;
        }
    }

    #define XPTR(TILE, RT) \
        ((const f32x4*)(x + (size_t)min((TILE) * RPB + (RT) * 16 + lc, n_rows - 1) * IND + lg * 8))

    // ---- 2-buffer ping-pong x prefetch (static register names, rule #20) ----
    f32x4 pa0, pa1, pa2, pa3, pb0, pb1, pb2, pb3;

    int tile = blockIdx.x;
    {   // prime: tile rt=0 -> A buffer
        const f32x4* p = XPTR(tile, 0);
        pa0 = p[0]; pa1 = p[1]; pa2 = p[8]; pa3 = p[9];
    }

    // one row-tile: consume CUR regs, prefetch (PT,PR) into NXT regs,
    // write normalized probs into the LDS half-tile (local rows (RT&1)*16+..)
    #define PROCESS(RT, C0, C1, C2, C3, N0, N1, N2, N3, PT, PR)                  \
    {                                                                            \
        {   const f32x4* np = XPTR(PT, PR);                                      \
            N0 = np[0]; N1 = np[1]; N2 = np[8]; N3 = np[9]; }                    \
        half8 a0, a1;                                                            \
        _Pragma("unroll")                                                        \
        for (int i = 0; i < 4; ++i) {                                            \
            a0[i] = (_Float16)C0[i]; a0[4 + i] = (_Float16)C1[i];                \
            a1[i] = (_Float16)C2[i]; a1[4 + i] = (_Float16)C3[i];                \
        }                                                                        \
        f32x4 c[NCT];                                                            \
        _Pragma("unroll")                                                        \
        for (int ct = 0; ct < NCT; ++ct) {                                       \
            f32x4 ci = {biasv[ct], biasv[ct], biasv[ct], biasv[ct]};             \
            ci = __builtin_amdgcn_mfma_f32_16x16x32_f16(a0, wf[ct][0], ci,0,0,0);\
            ci = __builtin_amdgcn_mfma_f32_16x16x32_f16(a1, wf[ct][1], ci,0,0,0);\
            c[ct] = ci;                                                          \
        }                                                                        \
        float m[4], s[4];                                                        \
        _Pragma("unroll")                                                        \
        for (int j = 0; j < 4; ++j) {                                            \
            float mj = c[0][j];                                                  \
            _Pragma("unroll")                                                    \
            for (int ct = 1; ct < NCT; ++ct) mj = fmaxf(mj, c[ct][j]);           \
            _Pragma("unroll")                                                    \
            for (int d = 1; d < 16; d <<= 1) mj = fmaxf(mj, __shfl_xor(mj,d,64));\
            m[j] = mj; s[j] = 0.0f;                                              \
        }                                                                        \
        _Pragma("unroll")                                                        \
        for (int ct = 0; ct < NCT; ++ct)                                         \
            _Pragma("unroll")                                                    \
            for (int j = 0; j < 4; ++j) {                                        \
                const float e = __expf(c[ct][j] - m[j]);                         \
                c[ct][j] = e; s[j] += e;                                         \
            }                                                                    \
        _Pragma("unroll")                                                        \
        for (int j = 0; j < 4; ++j) {                                            \
            _Pragma("unroll")                                                    \
            for (int d = 1; d < 16; d <<= 1) s[j] += __shfl_xor(s[j], d, 64);    \
            float inv = __builtin_amdgcn_rcpf(s[j]);                             \
            inv = inv * (2.0f - s[j] * inv);                                     \
            s[j] = inv;                                                          \
        }                                                                        \
        const int lr0 = (RT & 1) * 16 + lg * 4;                                  \
        _Pragma("unroll")                                                        \
        for (int ct = 0; ct < NCT; ++ct) {                                       \
            const int col = ct * 16 + lc;                                        \
            if (col < OUTD) {                                                    \
                _Pragma("unroll")                                                \
                for (int j = 0; j < 4; ++j)                                      \
                    ptile[(lr0 + j) * LROW + col] = c[ct][j] * s[j];             \
            }                                                                    \
        }                                                                        \
    }

    // drain one 32-row half: 12928B contiguous, 16B-aligned -> 13 x dwordx4
    #define DRAIN(HALF)                                                          \
    {                                                                            \
        float* obase = out1 + (size_t)tile * (RPB * OUTD) + (HALF) * HALF_WORDS; \
        if (row0 + RPB <= n_rows) {                                              \
            _Pragma("unroll")                                                    \
            for (int i = 0; i < 12; ++i) {                                       \
                const f32x4 v = *(const f32x4*)&ptile[i * 256 + lane * 4];       \
                *(f32x4*)(obase + i * 256 + lane * 4) = v;                       \
            }                                                                    \
            if (lane < 40) {                                                     \
                const f32x4 v = *(const f32x4*)&ptile[3072 + lane * 4];          \
                *(f32x4*)(obase + 3072 + lane * 4) = v;                          \
            }                                                                    \
        } else {  /* partial tile (never hit at N=1e6): guarded scalar */        \
            for (int r = 0; r < 32; ++r) {                                       \
                const int grr = row0 + (HALF) * 32 + r;                          \
                if (grr < n_rows)                                                \
                    for (int cc = lane; cc < OUTD; cc += 64)                     \
                        out1[(size_t)grr * OUTD + cc] = ptile[r * LROW + cc];    \
            }                                                                    \
        }                                                                        \
        /* interp from own LDS row: half 0 -> lanes 0..31, half 1 -> 32..63 */   \
        if ((lane >> 5) == (HALF) && gr < n_rows) {                              \
            const float Lv = ptile[(lane & 31) * LROW + Li];                     \
            const float Uv = ptile[(lane & 31) * LROW + Ui];                     \
            out_interp[gr] = Lv + (Uv - Lv) * inter;                             \
        }                                                                        \
    }

    for (; tile < n_tiles; tile += n_blocks) {
        const int row0 = tile * RPB;

        // own-row interp indices, kept in registers (lane owns row row0+lane)
        const int gr  = row0 + lane;
        const int grc = (gr < n_rows) ? gr : (n_rows - 1);
        const float tB = t[grc] * ngf;
        const float Uf = ceilf(tB);
        const float inter = 1.0f - (Uf - tB);
        float Lf = Uf - 1.0f;
        if (Lf < 0.0f) Lf += 1.0f;
        const int Li = (int)Lf, Ui = (int)Uf;

        const int  ntile = tile + n_blocks;
        const int  pt    = (ntile < n_tiles) ? ntile : tile;   // clamp: dummy reload

        PROCESS(0, pa0, pa1, pa2, pa3, pb0, pb1, pb2, pb3, tile, 1)
        PROCESS(1, pb0, pb1, pb2, pb3, pa0, pa1, pa2, pa3, tile, 2)
        DRAIN(0)
        PROCESS(2, pa0, pa1, pa2, pa3, pb0, pb1, pb2, pb3, tile, 3)
        PROCESS(3, pb0, pb1, pb2, pb3, pa0, pa1, pa2, pa3, pt,   0)
        DRAIN(1)
    }
    #undef DRAIN
    #undef PROCESS
    #undef XPTR
}

extern "C" void kernel_launch(void* const* d_in, const int* in_sizes, int n_in,
                              void* d_out, int out_size, void* d_ws, size_t ws_size,
                              hipStream_t stream) {
    const float* t  = (const float*)d_in[0];
    const float* x  = (const float*)d_in[1];
    const float* w  = (const float*)d_in[2];
    const float* b  = (const float*)d_in[3];
    const int*   ng = (const int*)d_in[4];
    const int n_rows = in_sizes[0];

    float* out1       = (float*)d_out;
    float* out_interp = out1 + (size_t)n_rows * OUTD;

    const int n_tiles  = (n_rows + RPB - 1) / RPB;   // 15625
    // 12.9KB LDS -> 12 blocks/CU; grid = full residency (R13: more is null)
    const int n_blocks = 3072;
    density_kernel<<<dim3(n_blocks), dim3(64), 0, stream>>>(
        t, x, w, b, ng, out1, out_interp, n_rows, n_tiles, n_blocks);
}

// Round 16
// 144.534 us; speedup vs baseline: 1.7702x; 1.0337x over previous
//
#include <hip/hip_runtime.h>
#include <math.h>

#define IND   64
#define OUTD  101
#define RPB   64
#define NCT   7              // 7 col-tiles x 16 = 112 padded cols
#define LROW  101            // LDS row stride (words)
#define QTR_WORDS (16 * OUTD)    // 1616 words = 6464 B per 16-row quarter

typedef _Float16 half8 __attribute__((ext_vector_type(8)));
typedef float    f32x4 __attribute__((ext_vector_type(4)));

// R15 proved the store stream was the limiter (LDS-staged linear drain:
// 170->149us). R16: shrink the staging unit 32->16 rows (12.9KB->6.5KB LDS)
// PURELY to unlock 16 blocks/CU (needs <=10KB), and launch 4096 blocks:
// tail makespan 15625/3072=5.09->6 rounds (18% idle) becomes
// 15625/4096=3.81->4 rounds (4.8%). Drain after every PROCESS also
// interleaves stores with compute 2x finer.
__global__ __launch_bounds__(64, 3) void density_kernel(
    const float* __restrict__ t,
    const float* __restrict__ x,
    const float* __restrict__ weight,
    const float* __restrict__ bias,
    const int*   __restrict__ num_grid,
    float* __restrict__ out1,
    float* __restrict__ out_interp,
    int n_rows, int n_tiles, int n_blocks)
{
    __shared__ float ptile[QTR_WORDS];   // 6464 B, reused for all 4 quarters

    const int lane = threadIdx.x;
    const int lc   = lane & 15;        // col-in-tile (R5 mapping)
    const int lg   = lane >> 4;        // k-group / row-group
    const float ngf = (float)num_grid[0];

    // ---- W fragments + bias ----
    half8 wf[NCT][2];
    float biasv[NCT];
#pragma unroll
    for (int ct = 0; ct < NCT; ++ct) {
        const int col  = ct * 16 + lc;
        const int colc = (col < OUTD) ? col : (OUTD - 1);
        biasv[ct] = (col < OUTD) ? bias[col] : -1e30f;   // pads killed via bias
#pragma unroll
        for (int kg = 0; kg < 2; ++kg) {
            half8 h;
#pragma unroll
            for (int j = 0; j < 8; ++j)
                h[j] = (_Float16)weight[(kg * 32 + lg * 8 + j) * OUTD + colc];
            wf[ct][kg] = h;
        }
    }

    #define XPTR(TILE, RT) \
        ((const f32x4*)(x + (size_t)min((TILE) * RPB + (RT) * 16 + lc, n_rows - 1) * IND + lg * 8))

    // ---- 2-buffer ping-pong x prefetch (static register names, rule #20) ----
    f32x4 pa0, pa1, pa2, pa3, pb0, pb1, pb2, pb3;

    int tile = blockIdx.x;
    {   // prime: tile rt=0 -> A buffer
        const f32x4* p = XPTR(tile, 0);
        pa0 = p[0]; pa1 = p[1]; pa2 = p[8]; pa3 = p[9];
    }

    // one row-tile: consume CUR regs, prefetch (PT,PR) into NXT regs,
    // write normalized probs into the 16-row LDS quarter (rows lg*4+j)
    #define PROCESS(RT, C0, C1, C2, C3, N0, N1, N2, N3, PT, PR)                  \
    {                                                                            \
        {   const f32x4* np = XPTR(PT, PR);                                      \
            N0 = np[0]; N1 = np[1]; N2 = np[8]; N3 = np[9]; }                    \
        half8 a0, a1;                                                            \
        _Pragma("unroll")                                                        \
        for (int i = 0; i < 4; ++i) {                                            \
            a0[i] = (_Float16)C0[i]; a0[4 + i] = (_Float16)C1[i];                \
            a1[i] = (_Float16)C2[i]; a1[4 + i] = (_Float16)C3[i];                \
        }                                                                        \
        f32x4 c[NCT];                                                            \
        _Pragma("unroll")                                                        \
        for (int ct = 0; ct < NCT; ++ct) {                                       \
            f32x4 ci = {biasv[ct], biasv[ct], biasv[ct], biasv[ct]};             \
            ci = __builtin_amdgcn_mfma_f32_16x16x32_f16(a0, wf[ct][0], ci,0,0,0);\
            ci = __builtin_amdgcn_mfma_f32_16x16x32_f16(a1, wf[ct][1], ci,0,0,0);\
            c[ct] = ci;                                                          \
        }                                                                        \
        float m[4], s[4];                                                        \
        _Pragma("unroll")                                                        \
        for (int j = 0; j < 4; ++j) {                                            \
            float mj = c[0][j];                                                  \
            _Pragma("unroll")                                                    \
            for (int ct = 1; ct < NCT; ++ct) mj = fmaxf(mj, c[ct][j]);           \
            _Pragma("unroll")                                                    \
            for (int d = 1; d < 16; d <<= 1) mj = fmaxf(mj, __shfl_xor(mj,d,64));\
            m[j] = mj; s[j] = 0.0f;                                              \
        }                                                                        \
        _Pragma("unroll")                                                        \
        for (int ct = 0; ct < NCT; ++ct)                                         \
            _Pragma("unroll")                                                    \
            for (int j = 0; j < 4; ++j) {                                        \
                const float e = __expf(c[ct][j] - m[j]);                         \
                c[ct][j] = e; s[j] += e;                                         \
            }                                                                    \
        _Pragma("unroll")                                                        \
        for (int j = 0; j < 4; ++j) {                                            \
            _Pragma("unroll")                                                    \
            for (int d = 1; d < 16; d <<= 1) s[j] += __shfl_xor(s[j], d, 64);    \
            float inv = __builtin_amdgcn_rcpf(s[j]);                             \
            inv = inv * (2.0f - s[j] * inv);                                     \
            s[j] = inv;                                                          \
        }                                                                        \
        _Pragma("unroll")                                                        \
        for (int ct = 0; ct < NCT; ++ct) {                                       \
            const int col = ct * 16 + lc;                                        \
            if (col < OUTD) {                                                    \
                _Pragma("unroll")                                                \
                for (int j = 0; j < 4; ++j)                                      \
                    ptile[(lg * 4 + j) * LROW + col] = c[ct][j] * s[j];          \
            }                                                                    \
        }                                                                        \
    }

    // drain one 16-row quarter: 6464B contiguous, 16B-aligned
    #define DRAIN(Q)                                                             \
    {                                                                            \
        float* obase = out1 + (size_t)tile * (RPB * OUTD) + (Q) * QTR_WORDS;     \
        if (row0 + RPB <= n_rows) {                                              \
            _Pragma("unroll")                                                    \
            for (int i = 0; i < 6; ++i) {                                        \
                const f32x4 v = *(const f32x4*)&ptile[i * 256 + lane * 4];       \
                *(f32x4*)(obase + i * 256 + lane * 4) = v;                       \
            }                                                                    \
            if (lane < 20) {                                                     \
                const f32x4 v = *(const f32x4*)&ptile[1536 + lane * 4];          \
                *(f32x4*)(obase + 1536 + lane * 4) = v;                          \
            }                                                                    \
        } else {  /* partial tile (never hit at N=1e6): guarded scalar */        \
            for (int r = 0; r < 16; ++r) {                                       \
                const int grr = row0 + (Q) * 16 + r;                             \
                if (grr < n_rows)                                                \
                    for (int cc = lane; cc < OUTD; cc += 64)                     \
                        out1[(size_t)grr * OUTD + cc] = ptile[r * LROW + cc];    \
            }                                                                    \
        }                                                                        \
        /* interp from own LDS row: quarter Q owns lanes Q*16..Q*16+15 */        \
        if ((lane >> 4) == (Q) && gr < n_rows) {                                 \
            const float Lv = ptile[(lane & 15) * LROW + Li];                     \
            const float Uv = ptile[(lane & 15) * LROW + Ui];                     \
            out_interp[gr] = Lv + (Uv - Lv) * inter;                             \
        }                                                                        \
    }

    for (; tile < n_tiles; tile += n_blocks) {
        const int row0 = tile * RPB;

        // own-row interp indices, kept in registers (lane owns row row0+lane)
        const int gr  = row0 + lane;
        const int grc = (gr < n_rows) ? gr : (n_rows - 1);
        const float tB = t[grc] * ngf;
        const float Uf = ceilf(tB);
        const float inter = 1.0f - (Uf - tB);
        float Lf = Uf - 1.0f;
        if (Lf < 0.0f) Lf += 1.0f;
        const int Li = (int)Lf, Ui = (int)Uf;

        const int  ntile = tile + n_blocks;
        const int  pt    = (ntile < n_tiles) ? ntile : tile;   // clamp: dummy reload

        PROCESS(0, pa0, pa1, pa2, pa3, pb0, pb1, pb2, pb3, tile, 1)
        DRAIN(0)
        PROCESS(1, pb0, pb1, pb2, pb3, pa0, pa1, pa2, pa3, tile, 2)
        DRAIN(1)
        PROCESS(2, pa0, pa1, pa2, pa3, pb0, pb1, pb2, pb3, tile, 3)
        DRAIN(2)
        PROCESS(3, pb0, pb1, pb2, pb3, pa0, pa1, pa2, pa3, pt,   0)
        DRAIN(3)
    }
    #undef DRAIN
    #undef PROCESS
    #undef XPTR
}

extern "C" void kernel_launch(void* const* d_in, const int* in_sizes, int n_in,
                              void* d_out, int out_size, void* d_ws, size_t ws_size,
                              hipStream_t stream) {
    const float* t  = (const float*)d_in[0];
    const float* x  = (const float*)d_in[1];
    const float* w  = (const float*)d_in[2];
    const float* b  = (const float*)d_in[3];
    const int*   ng = (const int*)d_in[4];
    const int n_rows = in_sizes[0];

    float* out1       = (float*)d_out;
    float* out_interp = out1 + (size_t)n_rows * OUTD;

    const int n_tiles  = (n_rows + RPB - 1) / RPB;   // 15625
    // 6.5KB LDS + 84 VGPR -> 16 one-wave blocks/CU; 4096 blocks -> 4-round
    // makespan (4.8% tail vs 18% at 3072).
    const int n_blocks = 4096;
    density_kernel<<<dim3(n_blocks), dim3(64), 0, stream>>>(
        t, x, w, b, ng, out1, out_interp, n_rows, n_tiles, n_blocks);
}

// Round 17
// 129.223 us; speedup vs baseline: 1.9800x; 1.1185x over previous
//
#include <hip/hip_runtime.h>
#include <math.h>

#define IND   64
#define OUTD  101
#define RPB   64
#define NCT   7              // 7 col-tiles x 16 = 112 padded cols
#define LROW  101            // LDS row stride (words)
#define QTR_WORDS (16 * OUTD)    // 1616 words = 6464 B per 16-row quarter

typedef _Float16 half8 __attribute__((ext_vector_type(8)));
typedef float    f32x4 __attribute__((ext_vector_type(4)));

// R15: LDS-staged fill-shaped drain (170->149). R16: 16-row quarters + 4096
// blocks (149->144.5). R17 single change: NONTEMPORAL drain stores. out1 is
// write-once (406MB) and was evicting x (256MB ~ L3 size) from L3 via
// write-allocate; nt stores stream past L2/L3, protecting x residency ->
// HBM reads drop toward compulsory. (R10's nt regression was on scattered
// 4B scalar stores; these are wave-contiguous 1KB dwordx4 = fill-shaped.)
__global__ __launch_bounds__(64, 3) void density_kernel(
    const float* __restrict__ t,
    const float* __restrict__ x,
    const float* __restrict__ weight,
    const float* __restrict__ bias,
    const int*   __restrict__ num_grid,
    float* __restrict__ out1,
    float* __restrict__ out_interp,
    int n_rows, int n_tiles, int n_blocks)
{
    __shared__ float ptile[QTR_WORDS];   // 6464 B, reused for all 4 quarters

    const int lane = threadIdx.x;
    const int lc   = lane & 15;        // col-in-tile (R5 mapping)
    const int lg   = lane >> 4;        // k-group / row-group
    const float ngf = (float)num_grid[0];

    // ---- W fragments + bias ----
    half8 wf[NCT][2];
    float biasv[NCT];
#pragma unroll
    for (int ct = 0; ct < NCT; ++ct) {
        const int col  = ct * 16 + lc;
        const int colc = (col < OUTD) ? col : (OUTD - 1);
        biasv[ct] = (col < OUTD) ? bias[col] : -1e30f;   // pads killed via bias
#pragma unroll
        for (int kg = 0; kg < 2; ++kg) {
            half8 h;
#pragma unroll
            for (int j = 0; j < 8; ++j)
                h[j] = (_Float16)weight[(kg * 32 + lg * 8 + j) * OUTD + colc];
            wf[ct][kg] = h;
        }
    }

    #define XPTR(TILE, RT) \
        ((const f32x4*)(x + (size_t)min((TILE) * RPB + (RT) * 16 + lc, n_rows - 1) * IND + lg * 8))

    // ---- 2-buffer ping-pong x prefetch (static register names, rule #20) ----
    f32x4 pa0, pa1, pa2, pa3, pb0, pb1, pb2, pb3;

    int tile = blockIdx.x;
    {   // prime: tile rt=0 -> A buffer
        const f32x4* p = XPTR(tile, 0);
        pa0 = p[0]; pa1 = p[1]; pa2 = p[8]; pa3 = p[9];
    }

    // one row-tile: consume CUR regs, prefetch (PT,PR) into NXT regs,
    // write normalized probs into the 16-row LDS quarter (rows lg*4+j)
    #define PROCESS(RT, C0, C1, C2, C3, N0, N1, N2, N3, PT, PR)                  \
    {                                                                            \
        {   const f32x4* np = XPTR(PT, PR);                                      \
            N0 = np[0]; N1 = np[1]; N2 = np[8]; N3 = np[9]; }                    \
        half8 a0, a1;                                                            \
        _Pragma("unroll")                                                        \
        for (int i = 0; i < 4; ++i) {                                            \
            a0[i] = (_Float16)C0[i]; a0[4 + i] = (_Float16)C1[i];                \
            a1[i] = (_Float16)C2[i]; a1[4 + i] = (_Float16)C3[i];                \
        }                                                                        \
        f32x4 c[NCT];                                                            \
        _Pragma("unroll")                                                        \
        for (int ct = 0; ct < NCT; ++ct) {                                       \
            f32x4 ci = {biasv[ct], biasv[ct], biasv[ct], biasv[ct]};             \
            ci = __builtin_amdgcn_mfma_f32_16x16x32_f16(a0, wf[ct][0], ci,0,0,0);\
            ci = __builtin_amdgcn_mfma_f32_16x16x32_f16(a1, wf[ct][1], ci,0,0,0);\
            c[ct] = ci;                                                          \
        }                                                                        \
        float m[4], s[4];                                                        \
        _Pragma("unroll")                                                        \
        for (int j = 0; j < 4; ++j) {                                            \
            float mj = c[0][j];                                                  \
            _Pragma("unroll")                                                    \
            for (int ct = 1; ct < NCT; ++ct) mj = fmaxf(mj, c[ct][j]);           \
            _Pragma("unroll")                                                    \
            for (int d = 1; d < 16; d <<= 1) mj = fmaxf(mj, __shfl_xor(mj,d,64));\
            m[j] = mj; s[j] = 0.0f;                                              \
        }                                                                        \
        _Pragma("unroll")                                                        \
        for (int ct = 0; ct < NCT; ++ct)                                         \
            _Pragma("unroll")                                                    \
            for (int j = 0; j < 4; ++j) {                                        \
                const float e = __expf(c[ct][j] - m[j]);                         \
                c[ct][j] = e; s[j] += e;                                         \
            }                                                                    \
        _Pragma("unroll")                                                        \
        for (int j = 0; j < 4; ++j) {                                            \
            _Pragma("unroll")                                                    \
            for (int d = 1; d < 16; d <<= 1) s[j] += __shfl_xor(s[j], d, 64);    \
            float inv = __builtin_amdgcn_rcpf(s[j]);                             \
            inv = inv * (2.0f - s[j] * inv);                                     \
            s[j] = inv;                                                          \
        }                                                                        \
        _Pragma("unroll")                                                        \
        for (int ct = 0; ct < NCT; ++ct) {                                       \
            const int col = ct * 16 + lc;                                        \
            if (col < OUTD) {                                                    \
                _Pragma("unroll")                                                \
                for (int j = 0; j < 4; ++j)                                      \
                    ptile[(lg * 4 + j) * LROW + col] = c[ct][j] * s[j];          \
            }                                                                    \
        }                                                                        \
    }

    // drain one 16-row quarter: 6464B contiguous, 16B-aligned, nt dwordx4
    #define DRAIN(Q)                                                             \
    {                                                                            \
        float* obase = out1 + (size_t)tile * (RPB * OUTD) + (Q) * QTR_WORDS;     \
        if (row0 + RPB <= n_rows) {                                              \
            _Pragma("unroll")                                                    \
            for (int i = 0; i < 6; ++i) {                                        \
                const f32x4 v = *(const f32x4*)&ptile[i * 256 + lane * 4];       \
                __builtin_nontemporal_store(v, (f32x4*)(obase + i * 256 + lane * 4)); \
            }                                                                    \
            if (lane < 20) {                                                     \
                const f32x4 v = *(const f32x4*)&ptile[1536 + lane * 4];          \
                __builtin_nontemporal_store(v, (f32x4*)(obase + 1536 + lane * 4)); \
            }                                                                    \
        } else {  /* partial tile (never hit at N=1e6): guarded scalar */        \
            for (int r = 0; r < 16; ++r) {                                       \
                const int grr = row0 + (Q) * 16 + r;                             \
                if (grr < n_rows)                                                \
                    for (int cc = lane; cc < OUTD; cc += 64)                     \
                        out1[(size_t)grr * OUTD + cc] = ptile[r * LROW + cc];    \
            }                                                                    \
        }                                                                        \
        /* interp from own LDS row: quarter Q owns lanes Q*16..Q*16+15 */        \
        if ((lane >> 4) == (Q) && gr < n_rows) {                                 \
            const float Lv = ptile[(lane & 15) * LROW + Li];                     \
            const float Uv = ptile[(lane & 15) * LROW + Ui];                     \
            out_interp[gr] = Lv + (Uv - Lv) * inter;                             \
        }                                                                        \
    }

    for (; tile < n_tiles; tile += n_blocks) {
        const int row0 = tile * RPB;

        // own-row interp indices, kept in registers (lane owns row row0+lane)
        const int gr  = row0 + lane;
        const int grc = (gr < n_rows) ? gr : (n_rows - 1);
        const float tB = t[grc] * ngf;
        const float Uf = ceilf(tB);
        const float inter = 1.0f - (Uf - tB);
        float Lf = Uf - 1.0f;
        if (Lf < 0.0f) Lf += 1.0f;
        const int Li = (int)Lf, Ui = (int)Uf;

        const int  ntile = tile + n_blocks;
        const int  pt    = (ntile < n_tiles) ? ntile : tile;   // clamp: dummy reload

        PROCESS(0, pa0, pa1, pa2, pa3, pb0, pb1, pb2, pb3, tile, 1)
        DRAIN(0)
        PROCESS(1, pb0, pb1, pb2, pb3, pa0, pa1, pa2, pa3, tile, 2)
        DRAIN(1)
        PROCESS(2, pa0, pa1, pa2, pa3, pb0, pb1, pb2, pb3, tile, 3)
        DRAIN(2)
        PROCESS(3, pb0, pb1, pb2, pb3, pa0, pa1, pa2, pa3, pt,   0)
        DRAIN(3)
    }
    #undef DRAIN
    #undef PROCESS
    #undef XPTR
}

extern "C" void kernel_launch(void* const* d_in, const int* in_sizes, int n_in,
                              void* d_out, int out_size, void* d_ws, size_t ws_size,
                              hipStream_t stream) {
    const float* t  = (const float*)d_in[0];
    const float* x  = (const float*)d_in[1];
    const float* w  = (const float*)d_in[2];
    const float* b  = (const float*)d_in[3];
    const int*   ng = (const int*)d_in[4];
    const int n_rows = in_sizes[0];

    float* out1       = (float*)d_out;
    float* out_interp = out1 + (size_t)n_rows * OUTD;

    const int n_tiles  = (n_rows + RPB - 1) / RPB;   // 15625
    const int n_blocks = 4096;                       // 16 one-wave blocks/CU
    density_kernel<<<dim3(n_blocks), dim3(64), 0, stream>>>(
        t, x, w, b, ng, out1, out_interp, n_rows, n_tiles, n_blocks);
}